// Round 14
// baseline (85.880 us; speedup 1.0000x reference)
//
#include <hip/hip_runtime.h>
#include <hip/hip_bf16.h>
#include <math.h>

#define BS   16
#define NQ   900
#define NCLS 1000
#define NT   100          // targets per batch (rows for LSA)
#define MQ   900          // queries (cols for LSA)
#define NCOL (BS * NT)    // 1600 total target columns
#define NSLOT 15          // ceil(MQ / 64)

// Compiler-only fence: pins program order of LDS ops around cross-lane
// handoffs. HW DS pipe is in-order per wave, so program order == visibility.
#define WAVE_FENCE() asm volatile("" ::: "memory")

__device__ __forceinline__ unsigned umin32(unsigned a, unsigned b) {
  return a < b ? a : b;
}

template <int CTRL>
__device__ __forceinline__ unsigned dpp_min_u32(unsigned x) {
  const unsigned o = (unsigned)__builtin_amdgcn_update_dpp(
      (int)x, (int)x, CTRL, 0xF, 0xF, false);
  return o < x ? o : x;
}

// full-wave u32 min -> uniform value
__device__ __forceinline__ unsigned wave_min_u32(unsigned x) {
  x = dpp_min_u32<0xB1>(x);    // quad_perm xor1
  x = dpp_min_u32<0x4E>(x);    // quad_perm xor2
  x = dpp_min_u32<0x114>(x);   // row_shr:4
  x = dpp_min_u32<0x118>(x);   // row_shr:8
  x = dpp_min_u32<0x142>(x);   // row_bcast15
  x = dpp_min_u32<0x143>(x);   // row_bcast31
  return (unsigned)__builtin_amdgcn_readlane((int)x, 63);
}

// order-preserving f32 -> u32 (min-compatible)
__device__ __forceinline__ unsigned f32key(float f) {
  unsigned e = __float_as_uint(f);
  return (e & 0x80000000u) ? ~e : (e | 0x80000000u);
}
__device__ __forceinline__ float f32unkey(unsigned k) {
  return __uint_as_float((k & 0x80000000u) ? (k ^ 0x80000000u) : ~k);
}

// load 4 consecutive target ids starting at column c0 (c0 % 4 == 0)
__device__ __forceinline__ int4 load_ids4(const int* __restrict__ ids, int c0,
                                          int id_stride) {
  if (id_stride == 1) {
    return *reinterpret_cast<const int4*>(ids + c0);
  } else {  // int64 storage: low words at even offsets
    const int4 a = *reinterpret_cast<const int4*>(ids + 2 * c0);
    const int4 b = *reinterpret_cast<const int4*>(ids + 2 * c0 + 4);
    return make_int4(a.x, a.z, b.x, b.z);
  }
}

// ---------------------------------------------------------------------------
// Kernel A: wave-per-row softmax stats + costT diagonal block. No barriers.
// ---------------------------------------------------------------------------
__global__ __launch_bounds__(256) void statcost_kernel(
    const float* __restrict__ logits, const float* __restrict__ boxes,
    const int* __restrict__ ids, const float* __restrict__ tbox,
    float* __restrict__ stats, float* __restrict__ costT, int id_stride) {
  const int tid = threadIdx.x, w = tid >> 6, lane = tid & 63;
  const int row = blockIdx.x * 4 + w;      // 0..14399
  const int b = row / NQ;
  const int q = row - b * NQ;

  __shared__ float lbuf[4][NCLS];
  float* lr = lbuf[w];

  const float4* l4 = (const float4*)(logits + (size_t)row * NCLS);
  float4 vv[4];
  float lmax = -INFINITY;
#pragma unroll
  for (int it = 0; it < 4; ++it) {
    const int idx = it * 64 + lane;
    if (idx < NCLS / 4) {
      vv[it] = l4[idx];
      ((float4*)lr)[idx] = vv[it];
      lmax = fmaxf(lmax,
                   fmaxf(fmaxf(vv[it].x, vv[it].y), fmaxf(vv[it].z, vv[it].w)));
    }
  }
  for (int o = 32; o > 0; o >>= 1) lmax = fmaxf(lmax, __shfl_xor(lmax, o, 64));
  float psum = 0.f;
#pragma unroll
  for (int it = 0; it < 4; ++it) {
    const int idx = it * 64 + lane;
    if (idx < NCLS / 4) {
      psum += __expf(vv[it].x - lmax) + __expf(vv[it].y - lmax) +
              __expf(vv[it].z - lmax) + __expf(vv[it].w - lmax);
    }
  }
  for (int o = 32; o > 0; o >>= 1) psum += __shfl_xor(psum, o, 64);
  if (lane == 0) { stats[2 * row] = lmax; stats[2 * row + 1] = psum; }

  WAVE_FENCE();   // LDS stage visible (in-order DS) before gathers
  const float4 bb = *reinterpret_cast<const float4*>(boxes + (size_t)row * 4);
  const float inv = 1.f / psum;
  for (int rr = lane; rr < NT; rr += 64) {
    const int j = b * NT + rr;
    const int id = ids[(size_t)j * id_stride];
    const float4 tb = *reinterpret_cast<const float4*>(tbox + (size_t)j * 4);
    float d = fabsf(bb.x - tb.x);
    d += fabsf(bb.y - tb.y);
    d += fabsf(bb.z - tb.z);
    d += fabsf(bb.w - tb.w);
    costT[((size_t)b * NT + rr) * MQ + q] = d - __expf(lr[id] - lmax) * inv;
  }
}

// ---------------------------------------------------------------------------
// Kernel B: per-row minima + argmin of costT. 1600 blocks x 64 lanes.
// ---------------------------------------------------------------------------
__global__ __launch_bounds__(64) void rowmin_kernel(
    const float* __restrict__ costT, float* __restrict__ u_w,
    int* __restrict__ amin_w) {
  const int bid = blockIdx.x;              // b*NT + r
  const float* rowp = costT + (size_t)bid * MQ;
  const int lane = threadIdx.x;
  const unsigned UMAX = 0xFFFFFFFFu;

  unsigned tv[NSLOT];
#pragma unroll
  for (int s = 0; s < NSLOT; ++s) {
    const int c = s * 64 + lane;
    tv[s] = (c < MQ) ? f32key(rowp[c]) : UMAX;
  }
  unsigned m[NSLOT];
#pragma unroll
  for (int s = 0; s < NSLOT; ++s) m[s] = tv[s];
#pragma unroll
  for (int st = 1; st < NSLOT; st <<= 1) {
#pragma unroll
    for (int s = 0; s + st < NSLOT; s += 2 * st) m[s] = umin32(m[s], m[s + st]);
  }
  const unsigned s_vb = wave_min_u32(m[0]);
  unsigned cj[NSLOT];
#pragma unroll
  for (int s = 0; s < NSLOT; ++s)
    cj[s] = (tv[s] == s_vb) ? (unsigned)(s * 64 + lane) : UMAX;
#pragma unroll
  for (int st = 1; st < NSLOT; st <<= 1) {
#pragma unroll
    for (int s = 0; s + st < NSLOT; s += 2 * st)
      cj[s] = umin32(cj[s], cj[s + st]);
  }
  const unsigned s_j = wave_min_u32(cj[0]);
  if (lane == 0) { u_w[bid] = f32unkey(s_vb); amin_w[bid] = (int)s_j; }
}

// ---------------------------------------------------------------------------
// Main kernel: blocks 0..15 = JV LSA (claims from precomputed argmins, ~6
// Dijkstras); blocks 16.. = wave-per-row C-matrix write, 4 cols/lane.
// ---------------------------------------------------------------------------
__global__ __launch_bounds__(256) void main_kernel(
    const float* __restrict__ logits, const float* __restrict__ boxes,
    const int* __restrict__ ids, const float* __restrict__ tbox,
    const float* __restrict__ stats, const float* __restrict__ costT,
    const float* __restrict__ u_w, const int* __restrict__ amin_w,
    float* __restrict__ C, float* __restrict__ out_i,
    float* __restrict__ out_j, int id_stride) {
  __shared__ float lbuf[4][NCLS];
  __shared__ int p[MQ + 1];
  __shared__ int way[MQ + 65];   // [901..964] absorb pad writes; [0] dummy
  __shared__ int cols[NT];

  if (blockIdx.x >= BS) {
    // -------- C-matrix path (wave-per-row, 4 cols/lane, no barriers) ------
    const int tid = threadIdx.x, w = tid >> 6, lane = tid & 63;
    const int row = (blockIdx.x - BS) * 4 + w;
    float* lr = lbuf[w];
    const float4* l4 = (const float4*)(logits + (size_t)row * NCLS);
#pragma unroll
    for (int it = 0; it < 4; ++it) {
      const int idx = it * 64 + lane;
      if (idx < NCLS / 4) ((float4*)lr)[idx] = l4[idx];
    }
    WAVE_FENCE();
    const float rmax = stats[2 * row];
    const float inv = 1.f / stats[2 * row + 1];
    const float4 bb = *reinterpret_cast<const float4*>(boxes + (size_t)row * 4);
    float* crow = C + (size_t)row * NCOL;
    // 6 full iterations of 256 columns (4/lane) + 64-column scalar tail
#pragma unroll
    for (int it = 0; it < 6; ++it) {
      const int c0 = it * 256 + lane * 4;
      const int4 id4 = load_ids4(ids, c0, id_stride);
      const float4 tb0 = *reinterpret_cast<const float4*>(tbox + (size_t)c0 * 4);
      const float4 tb1 =
          *reinterpret_cast<const float4*>(tbox + (size_t)(c0 + 1) * 4);
      const float4 tb2 =
          *reinterpret_cast<const float4*>(tbox + (size_t)(c0 + 2) * 4);
      const float4 tb3 =
          *reinterpret_cast<const float4*>(tbox + (size_t)(c0 + 3) * 4);
      float4 outv;
      {
        float d = fabsf(bb.x - tb0.x) + fabsf(bb.y - tb0.y) +
                  fabsf(bb.z - tb0.z) + fabsf(bb.w - tb0.w);
        outv.x = d - __expf(lr[id4.x] - rmax) * inv;
      }
      {
        float d = fabsf(bb.x - tb1.x) + fabsf(bb.y - tb1.y) +
                  fabsf(bb.z - tb1.z) + fabsf(bb.w - tb1.w);
        outv.y = d - __expf(lr[id4.y] - rmax) * inv;
      }
      {
        float d = fabsf(bb.x - tb2.x) + fabsf(bb.y - tb2.y) +
                  fabsf(bb.z - tb2.z) + fabsf(bb.w - tb2.w);
        outv.z = d - __expf(lr[id4.z] - rmax) * inv;
      }
      {
        float d = fabsf(bb.x - tb3.x) + fabsf(bb.y - tb3.y) +
                  fabsf(bb.z - tb3.z) + fabsf(bb.w - tb3.w);
        outv.w = d - __expf(lr[id4.w] - rmax) * inv;
      }
      *reinterpret_cast<float4*>(crow + c0) = outv;
    }
    {
      const int c = 1536 + lane;
      const int id = ids[(size_t)c * id_stride];
      const float4 tb = *reinterpret_cast<const float4*>(tbox + (size_t)c * 4);
      float d = fabsf(bb.x - tb.x) + fabsf(bb.y - tb.y) + fabsf(bb.z - tb.z) +
                fabsf(bb.w - tb.w);
      crow[c] = d - __expf(lr[id] - rmax) * inv;
    }
    return;
  }

  // ---------------- LSA path: one wave per batch ----------------
  if (threadIdx.x >= 64) return;
  const int b = blockIdx.x;
  const float* cost = costT + (size_t)b * NT * MQ;
  const int lane = threadIdx.x;
  const float FINF = __builtin_inff();
  const unsigned UMAX = 0xFFFFFFFFu;
  const unsigned UINFB = 0x7F800000u;    // +inf f32 bits

  float v[NSLOT];
  unsigned V32[NSLOT];
  float cfA[NSLOT], cfB[NSLOT];
  int jp[NSLOT];                 // (j << 7) | p[j] for this lane's columns

#pragma unroll
  for (int s = 0; s < NSLOT; ++s) v[s] = 0.f;
  for (int j = lane; j <= MQ; j += 64) p[j] = 0;
  for (int r2 = lane; r2 < NT; r2 += 64) cols[r2] = -7777;  // diag sentinel
  WAVE_FENCE();

  // u / amin from rowmin_kernel, distributed to registers
  float u0 = u_w[b * NT + lane];
  float u1 = (lane < NT - 64) ? u_w[b * NT + 64 + lane] : 0.f;
  const int a0 = amin_w[b * NT + lane];
  const int a1 = (lane < NT - 64) ? amin_w[b * NT + 64 + lane] : 0;

  // ---- Greedy pre-assignment, first-row-wins; all state in registers.
  unsigned long long cl0 = 0, cl1 = 0;   // row-claimed masks (uniform)
  {
    unsigned clm = 0;                    // per-lane claimed-column mask
    for (int r2 = 0; r2 < NT; ++r2) {
      const int aj0 = (r2 < 64) ? __builtin_amdgcn_readlane(a0, r2)
                                : __builtin_amdgcn_readlane(a1, r2 - 64);
      const int slot = aj0 >> 6;
      const bool owner = (lane == (aj0 & 63));
      const unsigned long long bl = __ballot(owner && ((clm >> slot) & 1u));
      if (bl == 0) {                     // column free -> claim it
        if (owner) { clm |= 1u << slot; p[aj0 + 1] = r2 + 1; }
        if (r2 < 64) cl0 |= 1ull << r2;
        else         cl1 |= 1ull << (r2 - 64);
      }
    }
  }
  WAVE_FENCE();   // claim p-writes visible before jp rebuild

#pragma unroll
  for (int s = 0; s < NSLOT; ++s) {
    const int c = s * 64 + lane;
    if (c < MQ) jp[s] = ((c + 1) << 7) | p[c + 1];
  }

  // ---- Dijkstra only for unclaimed rows (~6) ----
  for (int i = 1; i <= NT; ++i) {
    const int r = i - 1;
    const bool skip = (r < 64) ? ((cl0 >> r) & 1ull) : ((cl1 >> (r - 64)) & 1ull);
    if (skip) continue;

    {
      const float* crow = cost + (size_t)r * MQ;
#pragma unroll
      for (int s = 0; s < NSLOT; ++s) {
        const int c = s * 64 + lane;
        cfA[s] = (c < MQ) ? crow[c] : FINF;
      }
    }
    float uir;
    {
      const float uu = (r < 64) ? u0 : u1;
      uir = __uint_as_float(
          (unsigned)__builtin_amdgcn_readlane((int)__float_as_uint(uu),
                                              r & 63));
    }

    unsigned usedm = (lane >= MQ - 14 * 64) ? (1u << 14) : 0u;
    int tm0 = 0, tm1 = 0;
    float D = 0.f;
#pragma unroll
    for (int s = 0; s < NSLOT; ++s) V32[s] = UINFB;
    if (lane == 0) p[0] = i;
    WAVE_FENCE();

    int j0 = 0;
    int i0 = i;
    float ui0 = uir;

    auto iterate = [&](float (&CUR)[NSLOT], float (&NXT)[NSLOT]) -> bool {
      if (j0 > 0) {
        const int cz = j0 - 1;
        const bool own = (lane == (cz & 63));
        usedm |= own ? (1u << (cz >> 6)) : 0u;
      }
      {
        const int ri = i0 - 1;
        tm0 |= (lane == ri) ? 1 : 0;
        tm1 |= (lane == (ri - 64)) ? 1 : 0;
      }

      const float a = ui0 - D;
      unsigned tv[NSLOT];
#pragma unroll
      for (int s = 0; s < NSLOT; ++s) {
        const bool us = (usedm >> s) & 1u;
        const float rel = fmaxf(CUR[s] - a - v[s], 0.f);
        const unsigned rb = __float_as_uint(rel);
        const unsigned rbg = us ? UMAX : rb;
        const bool upd = rbg < V32[s];
        way[upd ? (s * 64 + lane + 1) : 0] = j0;
        V32[s] = upd ? rbg : V32[s];
        tv[s] = us ? UMAX : V32[s];
      }
      unsigned m[NSLOT];
#pragma unroll
      for (int s = 0; s < NSLOT; ++s) m[s] = tv[s];
#pragma unroll
      for (int st = 1; st < NSLOT; st <<= 1) {
#pragma unroll
        for (int s = 0; s + st < NSLOT; s += 2 * st)
          m[s] = umin32(m[s], m[s + st]);
      }
      const unsigned s_best = wave_min_u32(m[0]);
      const float Dnew = __uint_as_float(s_best);

      unsigned cj[NSLOT];
#pragma unroll
      for (int s = 0; s < NSLOT; ++s)
        cj[s] = (tv[s] == s_best) ? (unsigned)jp[s] : UMAX;
#pragma unroll
      for (int st = 1; st < NSLOT; st <<= 1) {
#pragma unroll
        for (int s = 0; s + st < NSLOT; s += 2 * st)
          cj[s] = umin32(cj[s], cj[s + st]);
      }
      const unsigned jpw = wave_min_u32(cj[0]);
      const int j1 = (int)(jpw >> 7);
      const int pj1 = (int)(jpw & 127u);

      if (pj1 != 0) {
        const float* crow = cost + (size_t)(pj1 - 1) * MQ;
#pragma unroll
        for (int s = 0; s < NSLOT; ++s) {
          const int c = s * 64 + lane;
          NXT[s] = (c < MQ) ? crow[c] : FINF;
        }
      }
      float unext = 0.f;
      if (pj1 != 0) {
        const int rr2 = pj1 - 1;
        const float uu = (rr2 < 64) ? u0 : u1;
        unext = __uint_as_float(
            (unsigned)__builtin_amdgcn_readlane((int)__float_as_uint(uu),
                                                rr2 & 63));
      }

      const float delta = Dnew - D;
      D = Dnew;
      u0 += tm0 ? delta : 0.f;
      u1 += tm1 ? delta : 0.f;

      j0 = j1; i0 = pj1; ui0 = unext;
      return pj1 != 0;
    };

    while (true) {
      if (!iterate(cfA, cfB)) break;
      if (!iterate(cfB, cfA)) break;
    }

    // deferred v fixup: used column's use-time offset == frozen V32 value
    {
      const float Dend = D;
#pragma unroll
      for (int s = 0; s < NSLOT; ++s) {
        const int c = s * 64 + lane;
        const bool us = (usedm >> s) & 1u;
        const float dv = __uint_as_float(V32[s]) - Dend;
        v[s] += (us && c < MQ) ? dv : 0.f;
      }
    }

    WAVE_FENCE();   // way[] relax writes before lane-0 walk
    if (lane == 0) {
      int ja = j0;
      while (ja != 0) { const int jb = way[ja]; p[ja] = p[jb]; ja = jb; }
    }
    WAVE_FENCE();   // p updates before all-lane jp rebuild
#pragma unroll
    for (int s = 0; s < NSLOT; ++s) {
      const int c = s * 64 + lane;
      if (c < MQ) jp[s] = ((c + 1) << 7) | p[c + 1];
    }
  }

  // extract assignment: cols[row] = column
  WAVE_FENCE();
  for (int j = lane + 1; j <= MQ; j += 64)
    if (p[j] > 0) cols[p[j] - 1] = j - 1;
  WAVE_FENCE();

  // order = argsort(cols); idx_i = cols[order], idx_j = order
  for (int r = lane; r < NT; r += 64) {
    const int c = cols[r];
    int rank = 0;
    for (int r2 = 0; r2 < NT; ++r2) rank += (cols[r2] < c);
    out_i[b * NT + rank] = (float)c;
    out_j[b * NT + rank] = (float)r;
  }
}

extern "C" void kernel_launch(void* const* d_in, const int* in_sizes, int n_in,
                              void* d_out, int out_size, void* d_ws,
                              size_t ws_size, hipStream_t stream) {
  const float* logits = (const float*)d_in[0];
  const float* boxes  = (const float*)d_in[1];
  const int*   ids    = (const int*)d_in[2];
  const float* tbox   = (const float*)d_in[3];

  float* C     = (float*)d_out;                      // 16*900*1600
  float* out_i = C + (size_t)BS * NQ * NCOL;         // 1600
  float* out_j = out_i + NCOL;                       // 1600

  float* costT = (float*)d_ws;                       // 16*100*900 floats
  float* stats = costT + (size_t)BS * NT * MQ;       // 2 * 14400 floats
  float* u_w   = stats + 2 * BS * NQ;                // 1600 floats
  int*   amin_w = (int*)(u_w + BS * NT);             // 1600 ints

  const int id_stride = (in_sizes[2] == 2 * NCOL) ? 2 : 1;

  statcost_kernel<<<BS * NQ / 4, 256, 0, stream>>>(logits, boxes, ids, tbox,
                                                   stats, costT, id_stride);
  rowmin_kernel<<<BS * NT, 64, 0, stream>>>(costT, u_w, amin_w);
  main_kernel<<<BS * NQ / 4 + BS, 256, 0, stream>>>(
      logits, boxes, ids, tbox, stats, costT, u_w, amin_w, C, out_i, out_j,
      id_stride);
}

// Round 16
// 83.630 us; speedup vs baseline: 1.0269x; 1.0269x over previous
//
#include <hip/hip_runtime.h>
#include <hip/hip_bf16.h>
#include <math.h>

#define BS   16
#define NQ   900
#define NCLS 1000
#define NT   100          // targets per batch (rows for LSA)
#define MQ   900          // queries (cols for LSA)
#define NCOL (BS * NT)    // 1600 total target columns
#define NSLOT 15          // ceil(MQ / 64)

typedef float f32x4 __attribute__((ext_vector_type(4)));

// Compiler-only fence (LSA path only): pins program order of LDS ops around
// cross-lane handoffs. HW DS pipe is in-order per wave.
#define WAVE_FENCE() asm volatile("" ::: "memory")

__device__ __forceinline__ unsigned umin32(unsigned a, unsigned b) {
  return a < b ? a : b;
}

template <int CTRL>
__device__ __forceinline__ unsigned dpp_min_u32(unsigned x) {
  const unsigned o = (unsigned)__builtin_amdgcn_update_dpp(
      (int)x, (int)x, CTRL, 0xF, 0xF, false);
  return o < x ? o : x;
}

// full-wave u32 min -> uniform value
__device__ __forceinline__ unsigned wave_min_u32(unsigned x) {
  x = dpp_min_u32<0xB1>(x);    // quad_perm xor1
  x = dpp_min_u32<0x4E>(x);    // quad_perm xor2
  x = dpp_min_u32<0x114>(x);   // row_shr:4
  x = dpp_min_u32<0x118>(x);   // row_shr:8
  x = dpp_min_u32<0x142>(x);   // row_bcast15
  x = dpp_min_u32<0x143>(x);   // row_bcast31
  return (unsigned)__builtin_amdgcn_readlane((int)x, 63);
}

// order-preserving f32 -> u32 (min-compatible)
__device__ __forceinline__ unsigned f32key(float f) {
  unsigned e = __float_as_uint(f);
  return (e & 0x80000000u) ? ~e : (e | 0x80000000u);
}
__device__ __forceinline__ float f32unkey(unsigned k) {
  return __uint_as_float((k & 0x80000000u) ? (k ^ 0x80000000u) : ~k);
}

// load 4 consecutive target ids starting at column c0 (c0 % 4 == 0)
__device__ __forceinline__ int4 load_ids4(const int* __restrict__ ids, int c0,
                                          int id_stride) {
  if (id_stride == 1) {
    return *reinterpret_cast<const int4*>(ids + c0);
  } else {  // int64 storage: low words at even offsets
    const int4 a = *reinterpret_cast<const int4*>(ids + 2 * c0);
    const int4 b = *reinterpret_cast<const int4*>(ids + 2 * c0 + 4);
    return make_int4(a.x, a.z, b.x, b.z);
  }
}

// ---------------------------------------------------------------------------
// Kernel A: wave-per-row softmax stats + costT diagonal block. No barriers,
// no fences — ds_write/ds_read on the same lbuf are alias-ordered already.
// ---------------------------------------------------------------------------
__global__ __launch_bounds__(256) void statcost_kernel(
    const float* __restrict__ logits, const float* __restrict__ boxes,
    const int* __restrict__ ids, const float* __restrict__ tbox,
    float* __restrict__ stats, float* __restrict__ costT, int id_stride) {
  const int tid = threadIdx.x, w = tid >> 6, lane = tid & 63;
  const int row = blockIdx.x * 4 + w;      // 0..14399
  const int b = row / NQ;
  const int q = row - b * NQ;

  __shared__ float lbuf[4][NCLS];
  float* lr = lbuf[w];

  const float4* l4 = (const float4*)(logits + (size_t)row * NCLS);
  float4 vv[4];
  float lmax = -INFINITY;
#pragma unroll
  for (int it = 0; it < 4; ++it) {
    const int idx = it * 64 + lane;
    if (idx < NCLS / 4) {
      vv[it] = l4[idx];
      ((float4*)lr)[idx] = vv[it];
      lmax = fmaxf(lmax,
                   fmaxf(fmaxf(vv[it].x, vv[it].y), fmaxf(vv[it].z, vv[it].w)));
    }
  }
  for (int o = 32; o > 0; o >>= 1) lmax = fmaxf(lmax, __shfl_xor(lmax, o, 64));
  float psum = 0.f;
#pragma unroll
  for (int it = 0; it < 4; ++it) {
    const int idx = it * 64 + lane;
    if (idx < NCLS / 4) {
      psum += __expf(vv[it].x - lmax) + __expf(vv[it].y - lmax) +
              __expf(vv[it].z - lmax) + __expf(vv[it].w - lmax);
    }
  }
  for (int o = 32; o > 0; o >>= 1) psum += __shfl_xor(psum, o, 64);
  if (lane == 0) { stats[2 * row] = lmax; stats[2 * row + 1] = psum; }

  const float4 bb = *reinterpret_cast<const float4*>(boxes + (size_t)row * 4);
  const float inv = 1.f / psum;
  for (int rr = lane; rr < NT; rr += 64) {
    const int j = b * NT + rr;
    const int id = ids[(size_t)j * id_stride];
    const float4 tb = *reinterpret_cast<const float4*>(tbox + (size_t)j * 4);
    float d = fabsf(bb.x - tb.x);
    d += fabsf(bb.y - tb.y);
    d += fabsf(bb.z - tb.z);
    d += fabsf(bb.w - tb.w);
    costT[((size_t)b * NT + rr) * MQ + q] = d - __expf(lr[id] - lmax) * inv;
  }
}

// ---------------------------------------------------------------------------
// Kernel B: per-row minima + argmin of costT. 1600 blocks x 64 lanes.
// ---------------------------------------------------------------------------
__global__ __launch_bounds__(64) void rowmin_kernel(
    const float* __restrict__ costT, float* __restrict__ u_w,
    int* __restrict__ amin_w) {
  const int bid = blockIdx.x;              // b*NT + r
  const float* rowp = costT + (size_t)bid * MQ;
  const int lane = threadIdx.x;
  const unsigned UMAX = 0xFFFFFFFFu;

  unsigned tv[NSLOT];
#pragma unroll
  for (int s = 0; s < NSLOT; ++s) {
    const int c = s * 64 + lane;
    tv[s] = (c < MQ) ? f32key(rowp[c]) : UMAX;
  }
  unsigned m[NSLOT];
#pragma unroll
  for (int s = 0; s < NSLOT; ++s) m[s] = tv[s];
#pragma unroll
  for (int st = 1; st < NSLOT; st <<= 1) {
#pragma unroll
    for (int s = 0; s + st < NSLOT; s += 2 * st) m[s] = umin32(m[s], m[s + st]);
  }
  const unsigned s_vb = wave_min_u32(m[0]);
  unsigned cj[NSLOT];
#pragma unroll
  for (int s = 0; s < NSLOT; ++s)
    cj[s] = (tv[s] == s_vb) ? (unsigned)(s * 64 + lane) : UMAX;
#pragma unroll
  for (int st = 1; st < NSLOT; st <<= 1) {
#pragma unroll
    for (int s = 0; s + st < NSLOT; s += 2 * st)
      cj[s] = umin32(cj[s], cj[s + st]);
  }
  const unsigned s_j = wave_min_u32(cj[0]);
  if (lane == 0) { u_w[bid] = f32unkey(s_vb); amin_w[bid] = (int)s_j; }
}

// ---------------------------------------------------------------------------
// Main kernel: blocks 0..15 = JV LSA; blocks 16.. = wave-per-row C-matrix
// write, 4 cols/lane, nontemporal stores (C is never re-read on-GPU; keeps
// logits L3-resident).
// ---------------------------------------------------------------------------
__global__ __launch_bounds__(256) void main_kernel(
    const float* __restrict__ logits, const float* __restrict__ boxes,
    const int* __restrict__ ids, const float* __restrict__ tbox,
    const float* __restrict__ stats, const float* __restrict__ costT,
    const float* __restrict__ u_w, const int* __restrict__ amin_w,
    float* __restrict__ C, float* __restrict__ out_i,
    float* __restrict__ out_j, int id_stride) {
  __shared__ float lbuf[4][NCLS];
  __shared__ int p[MQ + 1];
  __shared__ int way[MQ + 65];   // [901..964] absorb pad writes; [0] dummy
  __shared__ int cols[NT];

  if (blockIdx.x >= BS) {
    // -------- C-matrix path (wave-per-row, 4 cols/lane, no fences) --------
    const int tid = threadIdx.x, w = tid >> 6, lane = tid & 63;
    const int row = (blockIdx.x - BS) * 4 + w;
    float* lr = lbuf[w];
    const float4* l4 = (const float4*)(logits + (size_t)row * NCLS);
#pragma unroll
    for (int it = 0; it < 4; ++it) {
      const int idx = it * 64 + lane;
      if (idx < NCLS / 4) ((float4*)lr)[idx] = l4[idx];
    }
    const float rmax = stats[2 * row];
    const float inv = 1.f / stats[2 * row + 1];
    const float4 bb = *reinterpret_cast<const float4*>(boxes + (size_t)row * 4);
    float* crow = C + (size_t)row * NCOL;
    // 6 full iterations of 256 columns (4/lane) + 64-column tail
#pragma unroll
    for (int it = 0; it < 6; ++it) {
      const int c0 = it * 256 + lane * 4;
      const int4 id4 = load_ids4(ids, c0, id_stride);
      const float4 tb0 = *reinterpret_cast<const float4*>(tbox + (size_t)c0 * 4);
      const float4 tb1 =
          *reinterpret_cast<const float4*>(tbox + (size_t)(c0 + 1) * 4);
      const float4 tb2 =
          *reinterpret_cast<const float4*>(tbox + (size_t)(c0 + 2) * 4);
      const float4 tb3 =
          *reinterpret_cast<const float4*>(tbox + (size_t)(c0 + 3) * 4);
      f32x4 outv;
      {
        float d = fabsf(bb.x - tb0.x) + fabsf(bb.y - tb0.y) +
                  fabsf(bb.z - tb0.z) + fabsf(bb.w - tb0.w);
        outv.x = d - __expf(lr[id4.x] - rmax) * inv;
      }
      {
        float d = fabsf(bb.x - tb1.x) + fabsf(bb.y - tb1.y) +
                  fabsf(bb.z - tb1.z) + fabsf(bb.w - tb1.w);
        outv.y = d - __expf(lr[id4.y] - rmax) * inv;
      }
      {
        float d = fabsf(bb.x - tb2.x) + fabsf(bb.y - tb2.y) +
                  fabsf(bb.z - tb2.z) + fabsf(bb.w - tb2.w);
        outv.z = d - __expf(lr[id4.z] - rmax) * inv;
      }
      {
        float d = fabsf(bb.x - tb3.x) + fabsf(bb.y - tb3.y) +
                  fabsf(bb.z - tb3.z) + fabsf(bb.w - tb3.w);
        outv.w = d - __expf(lr[id4.w] - rmax) * inv;
      }
      __builtin_nontemporal_store(outv,
                                  reinterpret_cast<f32x4*>(crow + c0));
    }
    {
      const int c = 1536 + lane;
      const int id = ids[(size_t)c * id_stride];
      const float4 tb = *reinterpret_cast<const float4*>(tbox + (size_t)c * 4);
      float d = fabsf(bb.x - tb.x) + fabsf(bb.y - tb.y) + fabsf(bb.z - tb.z) +
                fabsf(bb.w - tb.w);
      __builtin_nontemporal_store(d - __expf(lr[id] - rmax) * inv, crow + c);
    }
    return;
  }

  // ---------------- LSA path: one wave per batch ----------------
  if (threadIdx.x >= 64) return;
  const int b = blockIdx.x;
  const float* cost = costT + (size_t)b * NT * MQ;
  const int lane = threadIdx.x;
  const float FINF = __builtin_inff();
  const unsigned UMAX = 0xFFFFFFFFu;
  const unsigned UINFB = 0x7F800000u;    // +inf f32 bits

  float v[NSLOT];
  unsigned V32[NSLOT];
  float cfA[NSLOT], cfB[NSLOT];
  int jp[NSLOT];                 // (j << 7) | p[j] for this lane's columns

#pragma unroll
  for (int s = 0; s < NSLOT; ++s) v[s] = 0.f;
  for (int j = lane; j <= MQ; j += 64) p[j] = 0;
  for (int r2 = lane; r2 < NT; r2 += 64) cols[r2] = -7777;  // diag sentinel
  WAVE_FENCE();

  // u / amin from rowmin_kernel, distributed to registers
  float u0 = u_w[b * NT + lane];
  float u1 = (lane < NT - 64) ? u_w[b * NT + 64 + lane] : 0.f;
  const int a0 = amin_w[b * NT + lane];
  const int a1 = (lane < NT - 64) ? amin_w[b * NT + 64 + lane] : 0;

  // ---- Greedy pre-assignment, first-row-wins; all state in registers.
  unsigned long long cl0 = 0, cl1 = 0;   // row-claimed masks (uniform)
  {
    unsigned clm = 0;                    // per-lane claimed-column mask
    for (int r2 = 0; r2 < NT; ++r2) {
      const int aj0 = (r2 < 64) ? __builtin_amdgcn_readlane(a0, r2)
                                : __builtin_amdgcn_readlane(a1, r2 - 64);
      const int slot = aj0 >> 6;
      const bool owner = (lane == (aj0 & 63));
      const unsigned long long bl = __ballot(owner && ((clm >> slot) & 1u));
      if (bl == 0) {                     // column free -> claim it
        if (owner) { clm |= 1u << slot; p[aj0 + 1] = r2 + 1; }
        if (r2 < 64) cl0 |= 1ull << r2;
        else         cl1 |= 1ull << (r2 - 64);
      }
    }
  }
  WAVE_FENCE();   // claim p-writes visible before jp rebuild

#pragma unroll
  for (int s = 0; s < NSLOT; ++s) {
    const int c = s * 64 + lane;
    if (c < MQ) jp[s] = ((c + 1) << 7) | p[c + 1];
  }

  // ---- Dijkstra only for unclaimed rows (~6) ----
  for (int i = 1; i <= NT; ++i) {
    const int r = i - 1;
    const bool skip = (r < 64) ? ((cl0 >> r) & 1ull) : ((cl1 >> (r - 64)) & 1ull);
    if (skip) continue;

    {
      const float* crow = cost + (size_t)r * MQ;
#pragma unroll
      for (int s = 0; s < NSLOT; ++s) {
        const int c = s * 64 + lane;
        cfA[s] = (c < MQ) ? crow[c] : FINF;
      }
    }
    float uir;
    {
      const float uu = (r < 64) ? u0 : u1;
      uir = __uint_as_float(
          (unsigned)__builtin_amdgcn_readlane((int)__float_as_uint(uu),
                                              r & 63));
    }

    unsigned usedm = (lane >= MQ - 14 * 64) ? (1u << 14) : 0u;
    int tm0 = 0, tm1 = 0;
    float D = 0.f;
#pragma unroll
    for (int s = 0; s < NSLOT; ++s) V32[s] = UINFB;
    if (lane == 0) p[0] = i;
    WAVE_FENCE();

    int j0 = 0;
    int i0 = i;
    float ui0 = uir;

    auto iterate = [&](float (&CUR)[NSLOT], float (&NXT)[NSLOT]) -> bool {
      if (j0 > 0) {
        const int cz = j0 - 1;
        const bool own = (lane == (cz & 63));
        usedm |= own ? (1u << (cz >> 6)) : 0u;
      }
      {
        const int ri = i0 - 1;
        tm0 |= (lane == ri) ? 1 : 0;
        tm1 |= (lane == (ri - 64)) ? 1 : 0;
      }

      const float a = ui0 - D;
      unsigned tv[NSLOT];
#pragma unroll
      for (int s = 0; s < NSLOT; ++s) {
        const bool us = (usedm >> s) & 1u;
        const float rel = fmaxf(CUR[s] - a - v[s], 0.f);
        const unsigned rb = __float_as_uint(rel);
        const unsigned rbg = us ? UMAX : rb;
        const bool upd = rbg < V32[s];
        way[upd ? (s * 64 + lane + 1) : 0] = j0;
        V32[s] = upd ? rbg : V32[s];
        tv[s] = us ? UMAX : V32[s];
      }
      unsigned m[NSLOT];
#pragma unroll
      for (int s = 0; s < NSLOT; ++s) m[s] = tv[s];
#pragma unroll
      for (int st = 1; st < NSLOT; st <<= 1) {
#pragma unroll
        for (int s = 0; s + st < NSLOT; s += 2 * st)
          m[s] = umin32(m[s], m[s + st]);
      }
      const unsigned s_best = wave_min_u32(m[0]);
      const float Dnew = __uint_as_float(s_best);

      unsigned cj[NSLOT];
#pragma unroll
      for (int s = 0; s < NSLOT; ++s)
        cj[s] = (tv[s] == s_best) ? (unsigned)jp[s] : UMAX;
#pragma unroll
      for (int st = 1; st < NSLOT; st <<= 1) {
#pragma unroll
        for (int s = 0; s + st < NSLOT; s += 2 * st)
          cj[s] = umin32(cj[s], cj[s + st]);
      }
      const unsigned jpw = wave_min_u32(cj[0]);
      const int j1 = (int)(jpw >> 7);
      const int pj1 = (int)(jpw & 127u);

      if (pj1 != 0) {
        const float* crow = cost + (size_t)(pj1 - 1) * MQ;
#pragma unroll
        for (int s = 0; s < NSLOT; ++s) {
          const int c = s * 64 + lane;
          NXT[s] = (c < MQ) ? crow[c] : FINF;
        }
      }
      float unext = 0.f;
      if (pj1 != 0) {
        const int rr2 = pj1 - 1;
        const float uu = (rr2 < 64) ? u0 : u1;
        unext = __uint_as_float(
            (unsigned)__builtin_amdgcn_readlane((int)__float_as_uint(uu),
                                                rr2 & 63));
      }

      const float delta = Dnew - D;
      D = Dnew;
      u0 += tm0 ? delta : 0.f;
      u1 += tm1 ? delta : 0.f;

      j0 = j1; i0 = pj1; ui0 = unext;
      return pj1 != 0;
    };

    while (true) {
      if (!iterate(cfA, cfB)) break;
      if (!iterate(cfB, cfA)) break;
    }

    // deferred v fixup: used column's use-time offset == frozen V32 value
    {
      const float Dend = D;
#pragma unroll
      for (int s = 0; s < NSLOT; ++s) {
        const int c = s * 64 + lane;
        const bool us = (usedm >> s) & 1u;
        const float dv = __uint_as_float(V32[s]) - Dend;
        v[s] += (us && c < MQ) ? dv : 0.f;
      }
    }

    WAVE_FENCE();   // way[] relax writes before lane-0 walk
    if (lane == 0) {
      int ja = j0;
      while (ja != 0) { const int jb = way[ja]; p[ja] = p[jb]; ja = jb; }
    }
    WAVE_FENCE();   // p updates before all-lane jp rebuild
#pragma unroll
    for (int s = 0; s < NSLOT; ++s) {
      const int c = s * 64 + lane;
      if (c < MQ) jp[s] = ((c + 1) << 7) | p[c + 1];
    }
  }

  // extract assignment: cols[row] = column
  WAVE_FENCE();
  for (int j = lane + 1; j <= MQ; j += 64)
    if (p[j] > 0) cols[p[j] - 1] = j - 1;
  WAVE_FENCE();

  // order = argsort(cols); idx_i = cols[order], idx_j = order
  for (int r = lane; r < NT; r += 64) {
    const int c = cols[r];
    int rank = 0;
    for (int r2 = 0; r2 < NT; ++r2) rank += (cols[r2] < c);
    out_i[b * NT + rank] = (float)c;
    out_j[b * NT + rank] = (float)r;
  }
}

extern "C" void kernel_launch(void* const* d_in, const int* in_sizes, int n_in,
                              void* d_out, int out_size, void* d_ws,
                              size_t ws_size, hipStream_t stream) {
  const float* logits = (const float*)d_in[0];
  const float* boxes  = (const float*)d_in[1];
  const int*   ids    = (const int*)d_in[2];
  const float* tbox   = (const float*)d_in[3];

  float* C     = (float*)d_out;                      // 16*900*1600
  float* out_i = C + (size_t)BS * NQ * NCOL;         // 1600
  float* out_j = out_i + NCOL;                       // 1600

  float* costT = (float*)d_ws;                       // 16*100*900 floats
  float* stats = costT + (size_t)BS * NT * MQ;       // 2 * 14400 floats
  float* u_w   = stats + 2 * BS * NQ;                // 1600 floats
  int*   amin_w = (int*)(u_w + BS * NT);             // 1600 ints

  const int id_stride = (in_sizes[2] == 2 * NCOL) ? 2 : 1;

  statcost_kernel<<<BS * NQ / 4, 256, 0, stream>>>(logits, boxes, ids, tbox,
                                                   stats, costT, id_stride);
  rowmin_kernel<<<BS * NT, 64, 0, stream>>>(costT, u_w, amin_w);
  main_kernel<<<BS * NQ / 4 + BS, 256, 0, stream>>>(
      logits, boxes, ids, tbox, stats, costT, u_w, amin_w, C, out_i, out_j,
      id_stride);
}